// Round 1
// baseline (158.298 us; speedup 1.0000x reference)
//
#include <hip/hip_runtime.h>

#define NN 2048     // nodes per graph
#define NG 64       // graphs
#define NE 16384    // edges per graph
#define BB 65536    // batch
#define META 64
#define TXD 8
#define NOISE 128

// ws layout (floats):
//   graph_out = ws            [64][128]            8192 floats
//   twT       = ws + 8192     [32][64]             2048 floats (trig_W transposed)
//   deg4      = ws + 10240    [64][4][2048] int    524288 ints
//   acc4      = ws + 534528   [64][4][2048] float  524288 floats
// total ~4.2 MB of the 256 MiB workspace.

// ---------------------------------------------------------------------------
// Kernel A1: per-(graph, quarter) degree partials. 256 blocks.
// Also zeroes graph_out (for fold's atomics) and transposes trig_W -> twT.
// All global writes are plain stores -> idempotent across graph replays.
// ---------------------------------------------------------------------------
__global__ __launch_bounds__(256) void deg_kernel(
    const int* __restrict__ edges,     // [64,2,16384]
    const float* __restrict__ trig_W,  // [64,32]
    int* __restrict__ deg4,            // [256,2048]
    float* __restrict__ twT,           // [32,64]
    float* __restrict__ graph_out)     // [64,128] (zeroed here)
{
    __shared__ int s_cnt[NN];          // 8 KB
    const int tid = threadIdx.x;
    const int g = blockIdx.x >> 2, q = blockIdx.x & 3;

    for (int n = tid; n < NN; n += 256) s_cnt[n] = 0;

    if (q == 0 && tid < NOISE) graph_out[g * NOISE + tid] = 0.0f;
    if (blockIdx.x == 1) {
        // transpose trig_W [64][32] -> twT [32][64]
        for (int idx = tid; idx < META * 32; idx += 256) {
            int i = idx >> 5, j = idx & 31;
            twT[j * META + i] = trig_W[idx];
        }
    }
    __syncthreads();

    const int4* __restrict__ ed =
        (const int4*)(edges + ((size_t)g * 2 + 1) * NE + q * 4096);
    #pragma unroll
    for (int k = 0; k < 4; ++k) {
        int4 d = ed[k * 256 + tid];
        atomicAdd(&s_cnt[d.x], 1);
        atomicAdd(&s_cnt[d.y], 1);
        atomicAdd(&s_cnt[d.z], 1);
        atomicAdd(&s_cnt[d.w], 1);
    }
    __syncthreads();

    int* __restrict__ dst = deg4 + (size_t)blockIdx.x * NN;
    for (int n = tid; n < NN; n += 256) dst[n] = s_cnt[n];
}

// ---------------------------------------------------------------------------
// Kernel A2: per-(graph, quarter) normalized-aggregation partials. 256 blocks.
// dinv from summed deg partials (+1 self loop); u64 fixed-point LDS accum;
// plain float store of the partial (idempotent).
// ---------------------------------------------------------------------------
__global__ __launch_bounds__(256) void acc_kernel(
    const int* __restrict__ edges,     // [64,2,16384]
    const int* __restrict__ deg4,      // [256,2048]
    float* __restrict__ acc4)          // [256,2048]
{
    __shared__ float              s_dinv[NN];   // 8 KB
    __shared__ unsigned long long s_acc[NN];    // 16 KB
    const int tid = threadIdx.x;
    const int g = blockIdx.x >> 2, q = blockIdx.x & 3;

    for (int n = tid; n < NN; n += 256) {
        int d = deg4[((size_t)g * 4 + 0) * NN + n]
              + deg4[((size_t)g * 4 + 1) * NN + n]
              + deg4[((size_t)g * 4 + 2) * NN + n]
              + deg4[((size_t)g * 4 + 3) * NN + n] + 1;
        s_dinv[n] = rsqrtf((float)d);
        s_acc[n] = 0ull;
    }
    __syncthreads();

    const int4* __restrict__ es =
        (const int4*)(edges + (size_t)g * 2 * NE + q * 4096);
    const int4* __restrict__ ed =
        (const int4*)(edges + ((size_t)g * 2 + 1) * NE + q * 4096);
    const float SCALE = 1099511627776.0f;  // 2^40
    #pragma unroll
    for (int k = 0; k < 4; ++k) {
        int4 s = es[k * 256 + tid];
        int4 d = ed[k * 256 + tid];
        atomicAdd(&s_acc[d.x], (unsigned long long)(s_dinv[s.x] * s_dinv[d.x] * SCALE));
        atomicAdd(&s_acc[d.y], (unsigned long long)(s_dinv[s.y] * s_dinv[d.y] * SCALE));
        atomicAdd(&s_acc[d.z], (unsigned long long)(s_dinv[s.z] * s_dinv[d.z] * SCALE));
        atomicAdd(&s_acc[d.w], (unsigned long long)(s_dinv[s.w] * s_dinv[d.w] * SCALE));
    }
    __syncthreads();

    float* __restrict__ dst = acc4 + (size_t)blockIdx.x * NN;
    for (int n = tid; n < NN; n += 256)
        dst[n] = (float)((double)s_acc[n] * 0x1p-40);
}

// ---------------------------------------------------------------------------
// Kernel B: fold. Sums the 4 partials, applies (acc + dinv^2)*w + b on the
// fly (no emb round-trip), then emb-chunk @ emb_W -> graph_out atomics.
// ---------------------------------------------------------------------------
__global__ __launch_bounds__(256) void fold_kernel(
    const int* __restrict__ deg4,      // [256,2048]
    const float* __restrict__ acc4,    // [256,2048]
    const float* __restrict__ gcn_w,
    const float* __restrict__ gcn_b,
    const float* __restrict__ emb_W,   // [2089,128]
    float* __restrict__ graph_out)     // [64,128], zeroed by deg_kernel
{
    __shared__ float s_e[128];
    __shared__ float s_red[128];
    const int tid = threadIdx.x;
    const int g = blockIdx.x >> 4, chunk = blockIdx.x & 15;
    const int n0 = chunk * 128;
    if (tid < 128) {
        const int n = n0 + tid;
        int d = deg4[((size_t)g * 4 + 0) * NN + n]
              + deg4[((size_t)g * 4 + 1) * NN + n]
              + deg4[((size_t)g * 4 + 2) * NN + n]
              + deg4[((size_t)g * 4 + 3) * NN + n] + 1;
        float di = rsqrtf((float)d);
        float a = acc4[((size_t)g * 4 + 0) * NN + n]
                + acc4[((size_t)g * 4 + 1) * NN + n]
                + acc4[((size_t)g * 4 + 2) * NN + n]
                + acc4[((size_t)g * 4 + 3) * NN + n] + di * di;
        s_e[tid] = a * gcn_w[0] + gcn_b[0];
    }
    __syncthreads();
    const int c = tid & 127, h = tid >> 7;
    const float* __restrict__ Wp = emb_W + (size_t)(n0 + h * 64) * NOISE + c;
    const float* __restrict__ ep = s_e + h * 64;
    float a0 = 0.f, a1 = 0.f, a2 = 0.f, a3 = 0.f;
    #pragma unroll
    for (int i = 0; i < 64; i += 4) {
        a0 = fmaf(ep[i + 0], Wp[(i + 0) * NOISE], a0);
        a1 = fmaf(ep[i + 1], Wp[(i + 1) * NOISE], a1);
        a2 = fmaf(ep[i + 2], Wp[(i + 2) * NOISE], a2);
        a3 = fmaf(ep[i + 3], Wp[(i + 3) * NOISE], a3);
    }
    float acc = (a0 + a1) + (a2 + a3);
    if (h == 1) s_red[c] = acc;
    __syncthreads();
    if (h == 0) atomicAdd(&graph_out[g * NOISE + c], acc + s_red[c]);
}

// ---------------------------------------------------------------------------
// Kernel C: main batched kernel. 32 rows/block, 2 barriers.
// DS-pipe slimmed: trig_W columns come from pre-transposed twT (global,
// L1-resident); tx/chain/bg read directly from global (wave-uniform);
// phase 2 is q-outer so w2 streams through 8 regs instead of 64.
// ---------------------------------------------------------------------------
#define ROWS 32
__global__ __launch_bounds__(256, 4) void main_kernel(
    const int* __restrict__ bg,          // [B]
    const float* __restrict__ chain,     // [B]
    const float* __restrict__ trig_in,   // [B,64]
    const float* __restrict__ txs,       // [B,8]
    const float* __restrict__ trig_b,    // [32]
    const float* __restrict__ twT,       // [32,64]
    const float* __restrict__ emb_W,     // [2089,128]
    const float* __restrict__ emb_b,     // [128]
    const float* __restrict__ graph_out, // [64,128]
    float* __restrict__ out)             // [B,128]
{
    __shared__ float s_td[ROWS * 68];    // trigger rows, stride 68 (8.7 KB)
    __shared__ float s_trig[ROWS * 36];  // relu'd trig, stride 36 (4.6 KB)

    const int tid = threadIdx.x;
    const int row0 = blockIdx.x * ROWS;

    // --- stage trigger rows: 32x64 floats = 512 float4 ---
    {
        const float4* __restrict__ gsrc =
            (const float4*)(trig_in + (size_t)row0 * META);
        #pragma unroll
        for (int k = 0; k < 2; ++k) {
            int t = tid + k * 256;
            int r = t >> 4, i4 = t & 15;
            *(float4*)&s_td[r * 68 + i4 * 4] = gsrc[t];
        }
    }

    const int n0 = (tid & 63) * 2;
    // hoisted small weights (overlap with staging latency)
    float2 w3[TXD];
    #pragma unroll
    for (int k = 0; k < TXD; ++k)
        w3[k] = *(const float2*)&emb_W[(size_t)(2081 + k) * NOISE + n0];
    const float2 w1   = *(const float2*)&emb_W[(size_t)2048 * NOISE + n0];
    const float2 bias = *(const float2*)&emb_b[n0];

    const int j0 = tid & 15;
    const int r0 = (tid >> 4) * 2;
    const float b0 = trig_b[j0], b1 = trig_b[j0 + 16];

    __syncthreads();

    // --- phase 1: trig = relu(td @ trig_W + b); cols {j0, j0+16} x 2 rows.
    //     B-operand (twT rows) from global: L1-hot 8 KB, VMEM pipe not DS. ---
    {
        const float* __restrict__ tw0 = twT + j0 * META;
        const float* __restrict__ tw1 = twT + (j0 + 16) * META;
        const float* __restrict__ td0 = s_td + r0 * 68;
        const float* __restrict__ td1 = s_td + (r0 + 1) * 68;
        float a00 = b0, a01 = b1, a10 = b0, a11 = b1;
        #pragma unroll
        for (int i = 0; i < META; i += 4) {
            float4 u0 = *(const float4*)(tw0 + i);
            float4 u1 = *(const float4*)(tw1 + i);
            float4 t0 = *(const float4*)(td0 + i);
            float4 t1 = *(const float4*)(td1 + i);
            a00 = fmaf(t0.x, u0.x, a00); a00 = fmaf(t0.y, u0.y, a00);
            a00 = fmaf(t0.z, u0.z, a00); a00 = fmaf(t0.w, u0.w, a00);
            a01 = fmaf(t0.x, u1.x, a01); a01 = fmaf(t0.y, u1.y, a01);
            a01 = fmaf(t0.z, u1.z, a01); a01 = fmaf(t0.w, u1.w, a01);
            a10 = fmaf(t1.x, u0.x, a10); a10 = fmaf(t1.y, u0.y, a10);
            a10 = fmaf(t1.z, u0.z, a10); a10 = fmaf(t1.w, u0.w, a10);
            a11 = fmaf(t1.x, u1.x, a11); a11 = fmaf(t1.y, u1.y, a11);
            a11 = fmaf(t1.z, u1.z, a11); a11 = fmaf(t1.w, u1.w, a11);
        }
        s_trig[r0 * 36 + j0]            = fmaxf(a00, 0.f);
        s_trig[r0 * 36 + j0 + 16]       = fmaxf(a01, 0.f);
        s_trig[(r0 + 1) * 36 + j0]      = fmaxf(a10, 0.f);
        s_trig[(r0 + 1) * 36 + j0 + 16] = fmaxf(a11, 0.f);
    }
    __syncthreads();

    // --- phase 2: 8 rows x 2 cols per thread, q-outer / p-inner ---
    const int wv = tid >> 6;   // rows wave-uniform -> LDS broadcasts
    float2 acc[8];

    // prologue: bias + graph_out gather + chain + tx contributions
    #pragma unroll
    for (int p = 0; p < 8; ++p) {
        const int r = p * 4 + wv;
        const int row = row0 + r;
        const int   gidx = bg[row];
        const float ch   = chain[row];
        const float2 go  = *(const float2*)&graph_out[gidx * NOISE + n0];
        const float4 t0  = *(const float4*)&txs[(size_t)row * TXD];
        const float4 t1  = *(const float4*)&txs[(size_t)row * TXD + 4];
        float ax = bias.x + go.x + ch * w1.x;
        float ay = bias.y + go.y + ch * w1.y;
        ax = fmaf(t0.x, w3[0].x, ax); ay = fmaf(t0.x, w3[0].y, ay);
        ax = fmaf(t0.y, w3[1].x, ax); ay = fmaf(t0.y, w3[1].y, ay);
        ax = fmaf(t0.z, w3[2].x, ax); ay = fmaf(t0.z, w3[2].y, ay);
        ax = fmaf(t0.w, w3[3].x, ax); ay = fmaf(t0.w, w3[3].y, ay);
        ax = fmaf(t1.x, w3[4].x, ax); ay = fmaf(t1.x, w3[4].y, ay);
        ax = fmaf(t1.y, w3[5].x, ax); ay = fmaf(t1.y, w3[5].y, ay);
        ax = fmaf(t1.z, w3[6].x, ax); ay = fmaf(t1.z, w3[6].y, ay);
        ax = fmaf(t1.w, w3[7].x, ax); ay = fmaf(t1.w, w3[7].y, ay);
        acc[p] = make_float2(ax, ay);
    }

    // trig @ W2: stream w2 4 rows at a time (8 regs), trig via LDS broadcast
    #pragma unroll
    for (int q = 0; q < 8; ++q) {
        const float2 w2q0 = *(const float2*)&emb_W[(size_t)(2049 + 4 * q + 0) * NOISE + n0];
        const float2 w2q1 = *(const float2*)&emb_W[(size_t)(2049 + 4 * q + 1) * NOISE + n0];
        const float2 w2q2 = *(const float2*)&emb_W[(size_t)(2049 + 4 * q + 2) * NOISE + n0];
        const float2 w2q3 = *(const float2*)&emb_W[(size_t)(2049 + 4 * q + 3) * NOISE + n0];
        #pragma unroll
        for (int p = 0; p < 8; ++p) {
            const int r = p * 4 + wv;
            const float4 t4 = *(const float4*)(s_trig + r * 36 + q * 4);
            acc[p].x = fmaf(t4.x, w2q0.x, acc[p].x); acc[p].y = fmaf(t4.x, w2q0.y, acc[p].y);
            acc[p].x = fmaf(t4.y, w2q1.x, acc[p].x); acc[p].y = fmaf(t4.y, w2q1.y, acc[p].y);
            acc[p].x = fmaf(t4.z, w2q2.x, acc[p].x); acc[p].y = fmaf(t4.z, w2q2.y, acc[p].y);
            acc[p].x = fmaf(t4.w, w2q3.x, acc[p].x); acc[p].y = fmaf(t4.w, w2q3.y, acc[p].y);
        }
    }

    #pragma unroll
    for (int p = 0; p < 8; ++p) {
        const int row = row0 + p * 4 + wv;
        *(float2*)&out[(size_t)row * NOISE + n0] = acc[p];
    }
}

extern "C" void kernel_launch(void* const* d_in, const int* in_sizes, int n_in,
                              void* d_out, int out_size, void* d_ws, size_t ws_size,
                              hipStream_t stream) {
    const int*   bg      = (const int*)d_in[0];
    const float* chain   = (const float*)d_in[1];
    const float* trig_in = (const float*)d_in[2];
    const float* txs     = (const float*)d_in[3];
    const int*   edges   = (const int*)d_in[4];
    const float* gcn_w   = (const float*)d_in[5];
    const float* gcn_b   = (const float*)d_in[6];
    const float* trig_W  = (const float*)d_in[7];
    const float* trig_b  = (const float*)d_in[8];
    const float* emb_W   = (const float*)d_in[9];
    const float* emb_b   = (const float*)d_in[10];
    float* out = (float*)d_out;

    float* wsf       = (float*)d_ws;
    float* graph_out = wsf;                       // 8192 floats
    float* twT       = wsf + 8192;                // 2048 floats
    int*   deg4      = (int*)(wsf + 10240);       // 524288 ints
    float* acc4      = wsf + 10240 + 524288;      // 524288 floats

    deg_kernel<<<NG * 4, 256, 0, stream>>>(edges, trig_W, deg4, twT, graph_out);
    acc_kernel<<<NG * 4, 256, 0, stream>>>(edges, deg4, acc4);
    fold_kernel<<<NG * 16, 256, 0, stream>>>(deg4, acc4, gcn_w, gcn_b, emb_W, graph_out);
    main_kernel<<<BB / ROWS, 256, 0, stream>>>(bg, chain, trig_in, txs, trig_b,
                                               twT, emb_W, emb_b, graph_out, out);
}